// Round 1
// baseline (4020.430 us; speedup 1.0000x reference)
//
#include <hip/hip_runtime.h>

// entmax-1.5 attention: B=8, H=8, S=1024, D=64, fp32.
// One block (256 threads) per query row; tau found by bisection on
// g(tau) = sum max(x - tau, 0)^2, root in [max-1, max] (shifted: [-1, 0]).

#define S_LEN 1024
#define D_DIM 64

__global__ __launch_bounds__(256) void entmax_attn_kernel(
    const float* __restrict__ Q, const float* __restrict__ K,
    const float* __restrict__ V, float* __restrict__ O)
{
    __shared__ float sc[S_LEN];     // scores -> p
    __shared__ float qs[D_DIM];
    __shared__ float red[4];
    __shared__ float outred[256];

    const int tid  = threadIdx.x;
    const int lane = tid & 63;
    const int wave = tid >> 6;
    const int row  = blockIdx.x;          // 0 .. B*H*S-1
    const int bh   = row >> 10;           // S = 1024

    const float* Kb = K + (size_t)bh * (S_LEN * D_DIM);
    const float* Vb = V + (size_t)bh * (S_LEN * D_DIM);
    const float* Qr = Q + (size_t)row * D_DIM;

    if (tid < D_DIM) qs[tid] = Qr[tid];
    __syncthreads();

    // ---- Phase 1: x_k = (q . k_k) / (sqrt(64) * 2) = dot/16 ----
    float x[4];
    #pragma unroll
    for (int j = 0; j < 4; ++j) {
        const int kk = tid + 256 * j;
        const float* kr = Kb + (size_t)kk * D_DIM;
        float acc = 0.f;
        #pragma unroll
        for (int d = 0; d < D_DIM; d += 4) {
            float4 kv = *(const float4*)(kr + d);
            acc = fmaf(qs[d+0], kv.x, acc);
            acc = fmaf(qs[d+1], kv.y, acc);
            acc = fmaf(qs[d+2], kv.z, acc);
            acc = fmaf(qs[d+3], kv.w, acc);
        }
        x[j] = acc * (1.0f / 16.0f);
    }

    // ---- max reduce over the row ----
    float m = fmaxf(fmaxf(x[0], x[1]), fmaxf(x[2], x[3]));
    #pragma unroll
    for (int off = 32; off; off >>= 1) m = fmaxf(m, __shfl_xor(m, off));
    if (lane == 0) red[wave] = m;
    __syncthreads();
    m = fmaxf(fmaxf(red[0], red[1]), fmaxf(red[2], red[3]));
    __syncthreads();

    #pragma unroll
    for (int j = 0; j < 4; ++j) x[j] -= m;   // now max(x) == 0

    // ---- bisection for tau in [-1, 0]: g(tau) = sum max(x-tau,0)^2 = 1 ----
    float lo = -1.0f, hi = 0.0f;
    for (int it = 0; it < 30; ++it) {
        const float mid = 0.5f * (lo + hi);
        float s = 0.f;
        #pragma unroll
        for (int j = 0; j < 4; ++j) {
            float t = fmaxf(x[j] - mid, 0.f);
            s = fmaf(t, t, s);
        }
        #pragma unroll
        for (int off = 32; off; off >>= 1) s += __shfl_xor(s, off);
        if (lane == 0) red[wave] = s;
        __syncthreads();
        s = red[0] + red[1] + red[2] + red[3];
        __syncthreads();                      // red reused next iter
        if (s >= 1.0f) lo = mid; else hi = mid;
    }
    const float tau = 0.5f * (lo + hi);

    // ---- p = max(x - tau, 0)^2, plus sum(p) for renormalization ----
    float ps = 0.f;
    #pragma unroll
    for (int j = 0; j < 4; ++j) {
        float t = fmaxf(x[j] - tau, 0.f);
        float p = t * t;
        sc[tid + 256 * j] = p;
        ps += p;
    }
    #pragma unroll
    for (int off = 32; off; off >>= 1) ps += __shfl_xor(ps, off);
    if (lane == 0) red[wave] = ps;
    __syncthreads();                          // also publishes sc[]
    const float inv = 1.0f / (red[0] + red[1] + red[2] + red[3]);

    // ---- PV: out[d] = sum_k p_k * V[k][d] ----
    const int d     = tid & 63;
    const int chunk = tid >> 6;
    const int k0    = chunk * 256;
    float acc = 0.f;
    for (int k = k0; k < k0 + 256; ++k)
        acc = fmaf(sc[k], Vb[(size_t)k * D_DIM + d], acc);
    outred[tid] = acc;
    __syncthreads();
    if (tid < 64) {
        float o = (outred[tid] + outred[64 + tid] +
                   outred[128 + tid] + outred[192 + tid]) * inv;
        O[(size_t)row * D_DIM + tid] = o;
    }
}

extern "C" void kernel_launch(void* const* d_in, const int* in_sizes, int n_in,
                              void* d_out, int out_size, void* d_ws, size_t ws_size,
                              hipStream_t stream) {
    const float* q = (const float*)d_in[0];
    const float* k = (const float*)d_in[1];
    const float* v = (const float*)d_in[2];
    float* o = (float*)d_out;
    // B*H*S = 8*8*1024 = 65536 rows
    entmax_attn_kernel<<<65536, 256, 0, stream>>>(q, k, v, o);
}

// Round 3
// 458.116 us; speedup vs baseline: 8.7760x; 8.7760x over previous
//
#include <hip/hip_runtime.h>

// entmax-1.5 attention, MFMA version. B=8,H=8,S=1024,D=64, fp32 in/out.
// Per block: Tq=16 query rows of one (b,h). GEMM1 Q.K^T -> scores (bf16 in
// LDS), per-row Newton solve for tau, p=(x-tau)+^2 -> bf16 LDS, GEMM2 P.V.

#define S_LEN 1024
#define D_DIM 64
#define TQ    16
#define TK    128
#define QPAD  72      // sQ row stride in bf16 elems (64+8: breaks bank stride, keeps 16B align)
#define KPAD  72      // sK row stride
#define VPAD  136     // sVt row stride (128+8)
#define PPAD  1032    // sP row stride (1024+8)

typedef short short8 __attribute__((ext_vector_type(8)));
typedef float f32x4  __attribute__((ext_vector_type(4)));

static __device__ __forceinline__ unsigned short f2bf(float f) {
    unsigned u = __builtin_bit_cast(unsigned, f);
    u += 0x7FFFu + ((u >> 16) & 1u);           // round to nearest even
    return (unsigned short)(u >> 16);
}
static __device__ __forceinline__ float bf2f(unsigned short b) {
    unsigned u = ((unsigned)b) << 16;
    return __builtin_bit_cast(float, u);
}

__global__ __launch_bounds__(256, 2) void entmax_attn_mfma(
    const float* __restrict__ Q, const float* __restrict__ K,
    const float* __restrict__ V, float* __restrict__ O)
{
    __shared__ unsigned short sQ[TQ * QPAD];    //  2304 B
    __shared__ unsigned short sP[TQ * PPAD];    // 33024 B
    __shared__ unsigned short sKV[TK * KPAD];   // 18432 B (also holds 64x136 V^T tile)
    __shared__ float sInv[TQ];

    const int tid  = threadIdx.x;
    const int lane = tid & 63;
    const int wave = tid >> 6;
    const int quad = lane >> 4;
    const int l15  = lane & 15;

    const int bh = blockIdx.x >> 6;   // 64 qtiles per bh
    const int qt = blockIdx.x & 63;

    const float* Qb = Q + ((size_t)bh * S_LEN + qt * TQ) * D_DIM;
    const float* Kb = K + (size_t)bh * S_LEN * D_DIM;
    const float* Vb = V + (size_t)bh * S_LEN * D_DIM;

    const int r8  = tid >> 4;         // 0..15
    const int d04 = (tid & 15) * 4;   // 0..60

    // ---- stage Q tile (16x64 fp32 -> bf16) ----
    {
        float4 qv = *(const float4*)(Qb + r8 * D_DIM + d04);
        *(ushort4*)(&sQ[r8 * QPAD + d04]) =
            make_ushort4(f2bf(qv.x), f2bf(qv.y), f2bf(qv.z), f2bf(qv.w));
    }

    // ================= GEMM1: scores[16][1024] = Q.K^T / 16 =================
    for (int kt = 0; kt < S_LEN / TK; ++kt) {
        #pragma unroll
        for (int c = 0; c < 8; ++c) {
            const int kr = r8 + 16 * c;
            float4 kv = *(const float4*)(Kb + (size_t)(kt * TK + kr) * D_DIM + d04);
            *(ushort4*)(&sKV[kr * KPAD + d04]) =
                make_ushort4(f2bf(kv.x), f2bf(kv.y), f2bf(kv.z), f2bf(kv.w));
        }
        __syncthreads();   // sK (and on kt==0, sQ) visible

        short8 a0 = *(const short8*)(&sQ[l15 * QPAD + quad * 8]);
        short8 a1 = *(const short8*)(&sQ[l15 * QPAD + 32 + quad * 8]);
        #pragma unroll
        for (int nt = 0; nt < 2; ++nt) {
            const int n0   = (wave * 2 + nt) * 16;
            const int krow = n0 + l15;
            short8 b0 = *(const short8*)(&sKV[krow * KPAD + quad * 8]);
            short8 b1 = *(const short8*)(&sKV[krow * KPAD + 32 + quad * 8]);
            f32x4 acc = {0.f, 0.f, 0.f, 0.f};
            acc = __builtin_amdgcn_mfma_f32_16x16x32_bf16(a0, b0, acc, 0, 0, 0);
            acc = __builtin_amdgcn_mfma_f32_16x16x32_bf16(a1, b1, acc, 0, 0, 0);
            #pragma unroll
            for (int i = 0; i < 4; ++i) {      // C layout: col=l15, row=quad*4+i
                const int row = quad * 4 + i;
                sP[row * PPAD + kt * TK + n0 + l15] = f2bf(acc[i] * 0.0625f);
            }
        }
        __syncthreads();   // protect sKV for next stage / sP complete at loop exit
    }

    // ================= entmax-1.5 per row: Newton for tau =================
    // wave w owns rows w*4 .. w*4+3; 1024 scores -> 16 regs/lane
    #pragma unroll 1
    for (int i = 0; i < 4; ++i) {
        const int r = wave * 4 + i;
        float xv[16];
        #pragma unroll
        for (int j = 0; j < 16; ++j)
            xv[j] = bf2f(sP[r * PPAD + lane + 64 * j]);
        float m = xv[0];
        #pragma unroll
        for (int j = 1; j < 16; ++j) m = fmaxf(m, xv[j]);
        #pragma unroll
        for (int off = 1; off < 64; off <<= 1) m = fmaxf(m, __shfl_xor(m, off));
        #pragma unroll
        for (int j = 0; j < 16; ++j) xv[j] -= m;   // max(xv)=0, root in [-1,0)

        // Newton from below on convex decreasing g(tau)=sum (x-tau)+^2:
        // g' = -2h, update tau += (g-1)/(2h); monotone, never overshoots.
        float tau = -1.0f;                          // g(-1) >= 1
        #pragma unroll 1
        for (int it = 0; it < 10; ++it) {
            float g = 0.f, h = 0.f;
            #pragma unroll
            for (int j = 0; j < 16; ++j) {
                float t = fmaxf(xv[j] - tau, 0.f);
                g = fmaf(t, t, g);
                h += t;
            }
            #pragma unroll
            for (int off = 1; off < 64; off <<= 1) {
                g += __shfl_xor(g, off);
                h += __shfl_xor(h, off);
            }
            tau += (g - 1.0f) / (2.0f * h);
        }

        float ps = 0.f;
        unsigned short pb[16];
        #pragma unroll
        for (int j = 0; j < 16; ++j) {
            float t = fmaxf(xv[j] - tau, 0.f);
            unsigned short b = f2bf(t * t);
            pb[j] = b;
            ps += bf2f(b);                          // sum of the ROUNDED p's
        }
        #pragma unroll
        for (int off = 1; off < 64; off <<= 1) ps += __shfl_xor(ps, off);
        #pragma unroll
        for (int j = 0; j < 16; ++j)
            sP[r * PPAD + lane + 64 * j] = pb[j];
        if (lane == 0) sInv[r] = 1.0f / ps;
    }
    __syncthreads();

    // ================= GEMM2: O[16][64] = P[16][1024] . V =================
    f32x4 oacc = {0.f, 0.f, 0.f, 0.f};
    const int n0 = wave * 16;                       // this wave's d-columns
    for (int kt = 0; kt < S_LEN / TK; ++kt) {
        #pragma unroll
        for (int c = 0; c < 8; ++c) {               // stage V tile TRANSPOSED
            const int kv = r8 + 16 * c;
            float4 vv = *(const float4*)(Vb + (size_t)(kt * TK + kv) * D_DIM + d04);
            sKV[(d04 + 0) * VPAD + kv] = f2bf(vv.x);
            sKV[(d04 + 1) * VPAD + kv] = f2bf(vv.y);
            sKV[(d04 + 2) * VPAD + kv] = f2bf(vv.z);
            sKV[(d04 + 3) * VPAD + kv] = f2bf(vv.w);
        }
        __syncthreads();
        #pragma unroll
        for (int ks = 0; ks < 4; ++ks) {
            short8 a = *(const short8*)(&sP[l15 * PPAD + kt * TK + ks * 32 + quad * 8]);
            short8 b = *(const short8*)(&sKV[(n0 + l15) * VPAD + ks * 32 + quad * 8]);
            oacc = __builtin_amdgcn_mfma_f32_16x16x32_bf16(a, b, oacc, 0, 0, 0);
        }
        __syncthreads();
    }

    // ---- epilogue: renormalize + store ----
    float* Ob = O + ((size_t)bh * S_LEN + qt * TQ) * D_DIM;
    #pragma unroll
    for (int i = 0; i < 4; ++i) {
        const int row = quad * 4 + i;
        Ob[row * D_DIM + n0 + l15] = oacc[i] * sInv[row];
    }
}

extern "C" void kernel_launch(void* const* d_in, const int* in_sizes, int n_in,
                              void* d_out, int out_size, void* d_ws, size_t ws_size,
                              hipStream_t stream) {
    const float* q = (const float*)d_in[0];
    const float* k = (const float*)d_in[1];
    const float* v = (const float*)d_in[2];
    float* o = (float*)d_out;
    // grid: 64 (b,h) pairs x 64 q-tiles of 16 rows
    entmax_attn_mfma<<<64 * 64, 256, 0, stream>>>(q, k, v, o);
}

// Round 4
// 265.783 us; speedup vs baseline: 15.1267x; 1.7236x over previous
//
#include <hip/hip_runtime.h>

// entmax-1.5 attention: B=8,H=8,S=1024,D=64, fp32 in/out.
// Prepass1: K -> bf16 ws. Prepass2: V -> bf16 transposed [bh][d][s] ws.
// Main: per block 16 q-rows; K/V tiles DMA'd via global_load_lds into
// XOR-swizzled LDS; GEMM1 Q.K^T -> bf16 scores in LDS; per-row Newton
// solve for entmax tau; GEMM2 P.V^T via MFMA.

#define S_LEN 1024
#define D_DIM 64
#define TQ    16
#define TK    128
#define QPAD  72      // sQ row stride (bf16 elems)
#define PPAD  1032    // sP row stride (bf16 elems)

typedef short  short8   __attribute__((ext_vector_type(8)));
typedef float  f32x4    __attribute__((ext_vector_type(4)));
typedef unsigned short ushort8v __attribute__((ext_vector_type(8)));

static __device__ __forceinline__ unsigned short f2bf(float f) {
    unsigned u = __builtin_bit_cast(unsigned, f);
    u += 0x7FFFu + ((u >> 16) & 1u);           // RNE
    return (unsigned short)(u >> 16);
}
static __device__ __forceinline__ float bf2f(unsigned short b) {
    unsigned u = ((unsigned)b) << 16;
    return __builtin_bit_cast(float, u);
}
static __device__ __forceinline__ void async16(const unsigned short* g, unsigned short* l) {
    __builtin_amdgcn_global_load_lds(
        (const __attribute__((address_space(1))) unsigned int*)g,
        (__attribute__((address_space(3))) unsigned int*)l, 16, 0, 0);
}

// ---------- prepass 1: fp32 -> bf16, 8 elems/thread ----------
__global__ __launch_bounds__(256) void convert_bf16(
    const float* __restrict__ in, unsigned short* __restrict__ out)
{
    const int idx = (blockIdx.x * 256 + threadIdx.x) * 8;
    float4 a = *(const float4*)(in + idx);
    float4 b = *(const float4*)(in + idx + 4);
    ushort8v r;
    r[0]=f2bf(a.x); r[1]=f2bf(a.y); r[2]=f2bf(a.z); r[3]=f2bf(a.w);
    r[4]=f2bf(b.x); r[5]=f2bf(b.y); r[6]=f2bf(b.z); r[7]=f2bf(b.w);
    *(ushort8v*)(out + idx) = r;
}

// ---------- prepass 2: V [bh][s][d] fp32 -> Vt [bh][d][s] bf16 ----------
__global__ __launch_bounds__(256) void transpose_v_bf16(
    const float* __restrict__ V, unsigned short* __restrict__ Vt)
{
    __shared__ float t[D_DIM * 65];            // [d][s_local], pad 65
    const int tid = threadIdx.x;
    const int bh = blockIdx.x >> 4;
    const int s0 = (blockIdx.x & 15) * 64;
    const float* Vb = V + ((size_t)bh * S_LEN + s0) * D_DIM;

    const int sr = tid >> 4, d4 = (tid & 15) * 4;
    #pragma unroll
    for (int ii = 0; ii < 4; ++ii) {
        const int s = sr + 16 * ii;
        float4 v = *(const float4*)(Vb + s * D_DIM + d4);
        t[(d4+0)*65 + s] = v.x; t[(d4+1)*65 + s] = v.y;
        t[(d4+2)*65 + s] = v.z; t[(d4+3)*65 + s] = v.w;
    }
    __syncthreads();
    const int d = tid >> 2, sq = tid & 3;
    ushort8v o0, o1;
    #pragma unroll
    for (int j = 0; j < 8; ++j) {
        o0[j] = f2bf(t[d*65 + sq*16 + j]);
        o1[j] = f2bf(t[d*65 + sq*16 + 8 + j]);
    }
    unsigned short* outp = Vt + ((size_t)bh * D_DIM + d) * S_LEN + s0 + sq * 16;
    *(ushort8v*)(outp)     = o0;
    *(ushort8v*)(outp + 8) = o1;
}

// ---------- main ----------
__global__ __launch_bounds__(256, 3) void entmax_attn_mfma(
    const float* __restrict__ Q, const unsigned short* __restrict__ Kbf,
    const unsigned short* __restrict__ Vt, float* __restrict__ O)
{
    __shared__ __align__(16) unsigned short sQ[TQ * QPAD];   //  2304 B
    __shared__ __align__(16) unsigned short sP[TQ * PPAD];   // 33024 B
    __shared__ __align__(16) unsigned short sT[TK * D_DIM];  // 16384 B (K tile / V^T tile)
    __shared__ float sInv[TQ];

    const int tid  = threadIdx.x;
    const int lane = tid & 63;
    const int wave = tid >> 6;
    const int quad = lane >> 4;
    const int l15  = lane & 15;

    const int bh = blockIdx.x >> 6;
    const int qt = blockIdx.x & 63;

    const float* Qb = Q + ((size_t)bh * S_LEN + qt * TQ) * D_DIM;
    const unsigned short* Kb = Kbf + (size_t)bh * S_LEN * D_DIM;
    const unsigned short* Vb = Vt  + (size_t)bh * D_DIM * S_LEN;

    // ---- stage Q tile (16x64 fp32 -> bf16, padded rows) ----
    {
        const int r8 = tid >> 4, d04 = (tid & 15) * 4;
        float4 qv = *(const float4*)(Qb + r8 * D_DIM + d04);
        *(ushort4*)(&sQ[r8 * QPAD + d04]) =
            make_ushort4(f2bf(qv.x), f2bf(qv.y), f2bf(qv.z), f2bf(qv.w));
    }

    // K-tile swizzle: physical 16B chunk p of row r holds logical chunk p^(r&7)
    const int kRowIn  = wave * 32 + (lane >> 3);      // +8*inst
    const int kChunk  = (lane & 7) ^ (lane >> 3);     // cl for inst base (r&7 = lane>>3)
    // ================= GEMM1: scores = Q.K^T / 16 =================
    for (int kt = 0; kt < S_LEN / TK; ++kt) {
        const unsigned short* Ksrc = Kb + (size_t)(kt * TK) * D_DIM;
        #pragma unroll
        for (int inst = 0; inst < 4; ++inst) {
            const int r  = kRowIn + inst * 8;         // (r&7)==lane>>3 for all inst
            async16(Ksrc + r * D_DIM + kChunk * 8,
                    &sT[(wave * 32 + inst * 8) * D_DIM]);
        }
        __syncthreads();

        short8 a0 = *(const short8*)(&sQ[l15 * QPAD + quad * 8]);
        short8 a1 = *(const short8*)(&sQ[l15 * QPAD + 32 + quad * 8]);
        #pragma unroll
        for (int nt = 0; nt < 2; ++nt) {
            const int n0   = (wave * 2 + nt) * 16;
            const int krow = n0 + l15;                // krow&7 == l15&7
            const int x7   = l15 & 7;
            short8 b0 = *(const short8*)(&sT[krow * D_DIM + (quad ^ x7) * 8]);
            short8 b1 = *(const short8*)(&sT[krow * D_DIM + ((quad + 4) ^ x7) * 8]);
            f32x4 acc = {0.f, 0.f, 0.f, 0.f};
            acc = __builtin_amdgcn_mfma_f32_16x16x32_bf16(a0, b0, acc, 0, 0, 0);
            acc = __builtin_amdgcn_mfma_f32_16x16x32_bf16(a1, b1, acc, 0, 0, 0);
            #pragma unroll
            for (int i = 0; i < 4; ++i) {             // C: col=l15, row=quad*4+i
                const int row = quad * 4 + i;
                sP[row * PPAD + kt * TK + n0 + l15] = f2bf(acc[i] * 0.0625f);
            }
        }
        __syncthreads();
    }

    // ================= entmax-1.5: 4 rows per wave, interleaved =================
    {
        const int r0 = wave * 4;
        float xv[4][16];
        #pragma unroll
        for (int i = 0; i < 4; ++i)
            #pragma unroll
            for (int j = 0; j < 16; ++j)
                xv[i][j] = bf2f(sP[(r0 + i) * PPAD + lane + 64 * j]);

        float mx[4];
        #pragma unroll
        for (int i = 0; i < 4; ++i) {
            float m = xv[i][0];
            #pragma unroll
            for (int j = 1; j < 16; ++j) m = fmaxf(m, xv[i][j]);
            mx[i] = m;
        }
        #pragma unroll
        for (int off = 1; off < 64; off <<= 1)
            #pragma unroll
            for (int i = 0; i < 4; ++i) mx[i] = fmaxf(mx[i], __shfl_xor(mx[i], off));
        #pragma unroll
        for (int i = 0; i < 4; ++i)
            #pragma unroll
            for (int j = 0; j < 16; ++j) xv[i][j] -= mx[i];

        // Newton from below on convex decreasing g(tau)=sum (x-tau)+^2
        float tau[4] = {-1.f, -1.f, -1.f, -1.f};
        #pragma unroll 1
        for (int it = 0; it < 10; ++it) {
            float g[4] = {0,0,0,0}, h[4] = {0,0,0,0};
            #pragma unroll
            for (int i = 0; i < 4; ++i)
                #pragma unroll
                for (int j = 0; j < 16; ++j) {
                    float t = fmaxf(xv[i][j] - tau[i], 0.f);
                    g[i] = fmaf(t, t, g[i]);
                    h[i] += t;
                }
            #pragma unroll
            for (int off = 1; off < 64; off <<= 1)
                #pragma unroll
                for (int i = 0; i < 4; ++i) {
                    g[i] += __shfl_xor(g[i], off);
                    h[i] += __shfl_xor(h[i], off);
                }
            #pragma unroll
            for (int i = 0; i < 4; ++i)
                tau[i] += (g[i] - 1.0f) / (2.0f * h[i]);
        }

        float ps[4] = {0,0,0,0};
        #pragma unroll
        for (int i = 0; i < 4; ++i)
            #pragma unroll
            for (int j = 0; j < 16; ++j) {
                float t = fmaxf(xv[i][j] - tau[i], 0.f);
                unsigned short b = f2bf(t * t);
                sP[(r0 + i) * PPAD + lane + 64 * j] = b;
                ps[i] += bf2f(b);
            }
        #pragma unroll
        for (int off = 1; off < 64; off <<= 1)
            #pragma unroll
            for (int i = 0; i < 4; ++i) ps[i] += __shfl_xor(ps[i], off);
        if (lane == 0) {
            #pragma unroll
            for (int i = 0; i < 4; ++i) sInv[r0 + i] = 1.0f / ps[i];
        }
    }
    __syncthreads();

    // ================= GEMM2: O = P . V  (B = V^T rows, swizzle c^(r&15)) ===
    f32x4 oacc = {0.f, 0.f, 0.f, 0.f};
    const int n0 = wave * 16;
    const int vRowIn = wave * 16 + (lane >> 4);       // +4*inst
    for (int kt = 0; kt < S_LEN / TK; ++kt) {
        const unsigned short* Vsrc = Vb + kt * TK;
        #pragma unroll
        for (int inst = 0; inst < 4; ++inst) {
            const int r  = vRowIn + inst * 4;
            const int cl = (lane & 15) ^ (inst * 4 + (lane >> 4)); // p^(r&15)
            async16(Vsrc + (size_t)r * S_LEN + cl * 8,
                    &sT[(wave * 16 + inst * 4) * TK]);
        }
        __syncthreads();
        #pragma unroll
        for (int ks = 0; ks < 4; ++ks) {
            short8 a = *(const short8*)(&sP[l15 * PPAD + kt * TK + ks * 32 + quad * 8]);
            const int pc = (ks * 4 + quad) ^ l15;     // vn&15 == l15
            short8 b = *(const short8*)(&sT[(n0 + l15) * TK + pc * 8]);
            oacc = __builtin_amdgcn_mfma_f32_16x16x32_bf16(a, b, oacc, 0, 0, 0);
        }
        __syncthreads();
    }

    // ---- epilogue ----
    float* Ob = O + ((size_t)bh * S_LEN + qt * TQ) * D_DIM;
    #pragma unroll
    for (int i = 0; i < 4; ++i) {
        const int row = quad * 4 + i;
        Ob[row * D_DIM + n0 + l15] = oacc[i] * sInv[row];
    }
}

extern "C" void kernel_launch(void* const* d_in, const int* in_sizes, int n_in,
                              void* d_out, int out_size, void* d_ws, size_t ws_size,
                              hipStream_t stream) {
    const float* q = (const float*)d_in[0];
    const float* k = (const float*)d_in[1];
    const float* v = (const float*)d_in[2];
    float* o = (float*)d_out;

    unsigned short* kbf = (unsigned short*)d_ws;                    // 8 MB
    unsigned short* vt  = kbf + (size_t)64 * S_LEN * D_DIM;         // 8 MB

    // K: 64*1024*64 = 4M elems / (256*8) = 2048 blocks
    convert_bf16<<<2048, 256, 0, stream>>>(k, kbf);
    // V transpose: 64 bh x 16 s-tiles
    transpose_v_bf16<<<1024, 256, 0, stream>>>(v, vt);
    // main: 64 bh x 64 q-tiles
    entmax_attn_mfma<<<4096, 256, 0, stream>>>(q, kbf, vt, o);
}

// Round 5
// 247.284 us; speedup vs baseline: 16.2584x; 1.0748x over previous
//
#include <hip/hip_runtime.h>

// entmax-1.5 attention: B=8,H=8,S=1024,D=64, fp32 in/out.
// Prepass (fused): K -> bf16 ws; V -> bf16 transposed [bh][d][s] ws.
// Main: 16 q-rows/block; K/V tiles DMA'd via global_load_lds into
// XOR-swizzled LDS; GEMM1 Q.K^T -> bf16 scores in LDS; per-row Newton
// solve for entmax tau; GEMM2 P.V^T via MFMA. Grid XCD-swizzled so each
// (b,h)'s 64 blocks share one XCD's L2 (2 MB K+V working set per XCD).

#define S_LEN 1024
#define D_DIM 64
#define TQ    16
#define TK    128
#define QPAD  72      // sQ row stride (bf16 elems)
#define PPAD  1032    // sP row stride (bf16 elems)

typedef short  short8   __attribute__((ext_vector_type(8)));
typedef float  f32x4    __attribute__((ext_vector_type(4)));
typedef unsigned short ushort8v __attribute__((ext_vector_type(8)));

static __device__ __forceinline__ unsigned short f2bf(float f) {
    unsigned u = __builtin_bit_cast(unsigned, f);
    u += 0x7FFFu + ((u >> 16) & 1u);           // RNE
    return (unsigned short)(u >> 16);
}
static __device__ __forceinline__ float bf2f(unsigned short b) {
    unsigned u = ((unsigned)b) << 16;
    return __builtin_bit_cast(float, u);
}
static __device__ __forceinline__ void async16(const unsigned short* g, unsigned short* l) {
    __builtin_amdgcn_global_load_lds(
        (const __attribute__((address_space(1))) unsigned int*)g,
        (__attribute__((address_space(3))) unsigned int*)l, 16, 0, 0);
}

// ---------- fused prepass: K convert (blocks 0..2047), V transpose (2048..3071) ----------
__global__ __launch_bounds__(256) void prep_kv(
    const float* __restrict__ K, const float* __restrict__ V,
    unsigned short* __restrict__ Kbf, unsigned short* __restrict__ Vt)
{
    __shared__ float t[D_DIM * 65];
    const int tid = threadIdx.x;
    if (blockIdx.x < 2048) {
        const int idx = (blockIdx.x * 256 + tid) * 8;
        float4 a = *(const float4*)(K + idx);
        float4 b = *(const float4*)(K + idx + 4);
        ushort8v r;
        r[0]=f2bf(a.x); r[1]=f2bf(a.y); r[2]=f2bf(a.z); r[3]=f2bf(a.w);
        r[4]=f2bf(b.x); r[5]=f2bf(b.y); r[6]=f2bf(b.z); r[7]=f2bf(b.w);
        *(ushort8v*)(Kbf + idx) = r;
    } else {
        const int blk = blockIdx.x - 2048;
        const int bh = blk >> 4;
        const int s0 = (blk & 15) * 64;
        const float* Vb = V + ((size_t)bh * S_LEN + s0) * D_DIM;
        const int sr = tid >> 4, d4 = (tid & 15) * 4;
        #pragma unroll
        for (int ii = 0; ii < 4; ++ii) {
            const int s = sr + 16 * ii;
            float4 v = *(const float4*)(Vb + s * D_DIM + d4);
            t[(d4+0)*65 + s] = v.x; t[(d4+1)*65 + s] = v.y;
            t[(d4+2)*65 + s] = v.z; t[(d4+3)*65 + s] = v.w;
        }
        __syncthreads();
        const int d = tid >> 2, sq = tid & 3;
        ushort8v o0, o1;
        #pragma unroll
        for (int j = 0; j < 8; ++j) {
            o0[j] = f2bf(t[d*65 + sq*16 + j]);
            o1[j] = f2bf(t[d*65 + sq*16 + 8 + j]);
        }
        unsigned short* outp = Vt + ((size_t)bh * D_DIM + d) * S_LEN + s0 + sq * 16;
        *(ushort8v*)(outp)     = o0;
        *(ushort8v*)(outp + 8) = o1;
    }
}

// ---------- main ----------
__global__ __launch_bounds__(256, 3) void entmax_attn_mfma(
    const float* __restrict__ Q, const unsigned short* __restrict__ Kbf,
    const unsigned short* __restrict__ Vt, float* __restrict__ O)
{
    __shared__ __align__(16) unsigned short sQ[TQ * QPAD];   //  2304 B
    __shared__ __align__(16) unsigned short sP[TQ * PPAD];   // 33024 B
    __shared__ __align__(16) unsigned short sT[TK * D_DIM];  // 16384 B (K tile / V^T tile)
    __shared__ float sInv[TQ];

    const int tid  = threadIdx.x;
    const int lane = tid & 63;
    const int wave = tid >> 6;
    const int quad = lane >> 4;
    const int l15  = lane & 15;

    // XCD swizzle: blocks round-robin to XCDs by blockIdx%8; pin each bh's
    // 64 blocks to one XCD: x=bh>>3 selects XCD, kk=((bh&7)<<6)|qt.
    const int x  = blockIdx.x & 7;
    const int kk = blockIdx.x >> 3;
    const int bh = (x << 3) | (kk >> 6);
    const int qt = kk & 63;

    const float* Qb = Q + ((size_t)bh * S_LEN + qt * TQ) * D_DIM;
    const unsigned short* Kb = Kbf + (size_t)bh * S_LEN * D_DIM;
    const unsigned short* Vb = Vt  + (size_t)bh * D_DIM * S_LEN;

    // ---- stage Q tile (16x64 fp32 -> bf16, padded rows) ----
    {
        const int r8 = tid >> 4, d04 = (tid & 15) * 4;
        float4 qv = *(const float4*)(Qb + r8 * D_DIM + d04);
        *(ushort4*)(&sQ[r8 * QPAD + d04]) =
            make_ushort4(f2bf(qv.x), f2bf(qv.y), f2bf(qv.z), f2bf(qv.w));
    }

    // K-tile swizzle: physical 16B chunk p of row r holds logical chunk p^(r&7)
    const int kRowIn  = wave * 32 + (lane >> 3);      // +8*inst
    const int kChunk  = (lane & 7) ^ (lane >> 3);     // cl for inst base (r&7 = lane>>3)
    // ================= GEMM1: scores = Q.K^T / 16 =================
    for (int kt = 0; kt < S_LEN / TK; ++kt) {
        const unsigned short* Ksrc = Kb + (size_t)(kt * TK) * D_DIM;
        #pragma unroll
        for (int inst = 0; inst < 4; ++inst) {
            const int r  = kRowIn + inst * 8;         // (r&7)==lane>>3 for all inst
            async16(Ksrc + r * D_DIM + kChunk * 8,
                    &sT[(wave * 32 + inst * 8) * D_DIM]);
        }
        __syncthreads();

        short8 a0 = *(const short8*)(&sQ[l15 * QPAD + quad * 8]);
        short8 a1 = *(const short8*)(&sQ[l15 * QPAD + 32 + quad * 8]);
        #pragma unroll
        for (int nt = 0; nt < 2; ++nt) {
            const int n0   = (wave * 2 + nt) * 16;
            const int krow = n0 + l15;                // krow&7 == l15&7
            const int x7   = l15 & 7;
            short8 b0 = *(const short8*)(&sT[krow * D_DIM + (quad ^ x7) * 8]);
            short8 b1 = *(const short8*)(&sT[krow * D_DIM + ((quad + 4) ^ x7) * 8]);
            f32x4 acc = {0.f, 0.f, 0.f, 0.f};
            acc = __builtin_amdgcn_mfma_f32_16x16x32_bf16(a0, b0, acc, 0, 0, 0);
            acc = __builtin_amdgcn_mfma_f32_16x16x32_bf16(a1, b1, acc, 0, 0, 0);
            #pragma unroll
            for (int i = 0; i < 4; ++i) {             // C: col=l15, row=quad*4+i
                const int row = quad * 4 + i;
                sP[row * PPAD + kt * TK + n0 + l15] = f2bf(acc[i] * 0.0625f);
            }
        }
        __syncthreads();
    }

    // ================= entmax-1.5: 4 rows per wave, interleaved =================
    {
        const int r0 = wave * 4;
        float xv[4][16];
        #pragma unroll
        for (int i = 0; i < 4; ++i)
            #pragma unroll
            for (int j = 0; j < 16; ++j)
                xv[i][j] = bf2f(sP[(r0 + i) * PPAD + lane + 64 * j]);

        float mx[4];
        #pragma unroll
        for (int i = 0; i < 4; ++i) {
            float m = xv[i][0];
            #pragma unroll
            for (int j = 1; j < 16; ++j) m = fmaxf(m, xv[i][j]);
            mx[i] = m;
        }
        #pragma unroll
        for (int off = 1; off < 64; off <<= 1)
            #pragma unroll
            for (int i = 0; i < 4; ++i) mx[i] = fmaxf(mx[i], __shfl_xor(mx[i], off));
        #pragma unroll
        for (int i = 0; i < 4; ++i)
            #pragma unroll
            for (int j = 0; j < 16; ++j) xv[i][j] -= mx[i];

        // Newton from below on convex decreasing g(tau)=sum (x-tau)+^2
        float tau[4] = {-1.f, -1.f, -1.f, -1.f};
        #pragma unroll 1
        for (int it = 0; it < 8; ++it) {
            float g[4] = {0,0,0,0}, h[4] = {0,0,0,0};
            #pragma unroll
            for (int i = 0; i < 4; ++i)
                #pragma unroll
                for (int j = 0; j < 16; ++j) {
                    float t = fmaxf(xv[i][j] - tau[i], 0.f);
                    g[i] = fmaf(t, t, g[i]);
                    h[i] += t;
                }
            #pragma unroll
            for (int off = 1; off < 64; off <<= 1)
                #pragma unroll
                for (int i = 0; i < 4; ++i) {
                    g[i] += __shfl_xor(g[i], off);
                    h[i] += __shfl_xor(h[i], off);
                }
            #pragma unroll
            for (int i = 0; i < 4; ++i)
                tau[i] += (g[i] - 1.0f) / (2.0f * h[i]);
        }

        float ps[4] = {0,0,0,0};
        #pragma unroll
        for (int i = 0; i < 4; ++i)
            #pragma unroll
            for (int j = 0; j < 16; ++j) {
                float t = fmaxf(xv[i][j] - tau[i], 0.f);
                unsigned short b = f2bf(t * t);
                sP[(r0 + i) * PPAD + lane + 64 * j] = b;
                ps[i] += bf2f(b);
            }
        #pragma unroll
        for (int off = 1; off < 64; off <<= 1)
            #pragma unroll
            for (int i = 0; i < 4; ++i) ps[i] += __shfl_xor(ps[i], off);
        if (lane == 0) {
            #pragma unroll
            for (int i = 0; i < 4; ++i) sInv[r0 + i] = 1.0f / ps[i];
        }
    }
    __syncthreads();

    // ================= GEMM2: O = P . V  (B = V^T rows, swizzle c^(r&15)) ===
    f32x4 oacc = {0.f, 0.f, 0.f, 0.f};
    const int n0 = wave * 16;
    const int vRowIn = wave * 16 + (lane >> 4);       // +4*inst
    for (int kt = 0; kt < S_LEN / TK; ++kt) {
        const unsigned short* Vsrc = Vb + kt * TK;
        #pragma unroll
        for (int inst = 0; inst < 4; ++inst) {
            const int r  = vRowIn + inst * 4;
            const int cl = (lane & 15) ^ (inst * 4 + (lane >> 4)); // p^(r&15)
            async16(Vsrc + (size_t)r * S_LEN + cl * 8,
                    &sT[(wave * 16 + inst * 4) * TK]);
        }
        __syncthreads();
        #pragma unroll
        for (int ks = 0; ks < 4; ++ks) {
            short8 a = *(const short8*)(&sP[l15 * PPAD + kt * TK + ks * 32 + quad * 8]);
            const int pc = (ks * 4 + quad) ^ l15;     // vn&15 == l15
            short8 b = *(const short8*)(&sT[(n0 + l15) * TK + pc * 8]);
            oacc = __builtin_amdgcn_mfma_f32_16x16x32_bf16(a, b, oacc, 0, 0, 0);
        }
        __syncthreads();
    }

    // ---- epilogue ----
    float* Ob = O + ((size_t)bh * S_LEN + qt * TQ) * D_DIM;
    #pragma unroll
    for (int i = 0; i < 4; ++i) {
        const int row = quad * 4 + i;
        Ob[row * D_DIM + n0 + l15] = oacc[i] * sInv[row];
    }
}

extern "C" void kernel_launch(void* const* d_in, const int* in_sizes, int n_in,
                              void* d_out, int out_size, void* d_ws, size_t ws_size,
                              hipStream_t stream) {
    const float* q = (const float*)d_in[0];
    const float* k = (const float*)d_in[1];
    const float* v = (const float*)d_in[2];
    float* o = (float*)d_out;

    unsigned short* kbf = (unsigned short*)d_ws;                    // 8 MB
    unsigned short* vt  = kbf + (size_t)64 * S_LEN * D_DIM;         // 8 MB

    // fused prepass: 2048 K-convert blocks + 1024 V-transpose blocks
    prep_kv<<<3072, 256, 0, stream>>>(k, v, kbf, vt);
    // main: 64 bh x 64 q-tiles, XCD-swizzled
    entmax_attn_mfma<<<4096, 256, 0, stream>>>(q, kbf, vt, o);
}

// Round 6
// 206.993 us; speedup vs baseline: 19.4230x; 1.1946x over previous
//
#include <hip/hip_runtime.h>

// entmax-1.5 attention: B=8,H=8,S=1024,D=64, fp32 in/out.
// Prepass (fused): K -> bf16 ws; V -> bf16 transposed [bh][d][s] ws.
// Main: 16 q-rows/block; double-buffered 64x64 K/V tiles DMA'd via
// global_load_lds (prefetch overlapped with compute); GEMM1 Q.K^T -> bf16
// scores in LDS; per-row Newton for entmax tau (wave-local, b128 LDS,
// 16-lane reduces); GEMM2 P.V^T. Grid XCD-swizzled for L2 locality.

#define S_LEN 1024
#define D_DIM 64
#define TQ    16
#define TK    64
#define NT    (S_LEN / TK)    // 16 tiles
#define QPAD  72              // sQ row stride (bf16 elems)
#define PPAD  1032            // sP row stride (bf16 elems)

typedef short  short8   __attribute__((ext_vector_type(8)));
typedef float  f32x4    __attribute__((ext_vector_type(4)));
typedef unsigned short ushort8v __attribute__((ext_vector_type(8)));

static __device__ __forceinline__ unsigned short f2bf(float f) {
    unsigned u = __builtin_bit_cast(unsigned, f);
    u += 0x7FFFu + ((u >> 16) & 1u);           // RNE
    return (unsigned short)(u >> 16);
}
static __device__ __forceinline__ float bf_lo(unsigned u) {
    return __builtin_bit_cast(float, u << 16);
}
static __device__ __forceinline__ float bf_hi(unsigned u) {
    return __builtin_bit_cast(float, u & 0xFFFF0000u);
}
static __device__ __forceinline__ void async16(const unsigned short* g, unsigned short* l) {
    __builtin_amdgcn_global_load_lds(
        (const __attribute__((address_space(1))) unsigned int*)g,
        (__attribute__((address_space(3))) unsigned int*)l, 16, 0, 0);
}

// ---------- fused prepass: K convert (blocks 0..2047), V transpose (2048..3071) ----------
__global__ __launch_bounds__(256) void prep_kv(
    const float* __restrict__ K, const float* __restrict__ V,
    unsigned short* __restrict__ Kbf, unsigned short* __restrict__ Vt)
{
    __shared__ float t[D_DIM * 65];
    const int tid = threadIdx.x;
    if (blockIdx.x < 2048) {
        const int idx = (blockIdx.x * 256 + tid) * 8;
        float4 a = *(const float4*)(K + idx);
        float4 b = *(const float4*)(K + idx + 4);
        ushort8v r;
        r[0]=f2bf(a.x); r[1]=f2bf(a.y); r[2]=f2bf(a.z); r[3]=f2bf(a.w);
        r[4]=f2bf(b.x); r[5]=f2bf(b.y); r[6]=f2bf(b.z); r[7]=f2bf(b.w);
        *(ushort8v*)(Kbf + idx) = r;
    } else {
        const int blk = blockIdx.x - 2048;
        const int bh = blk >> 4;
        const int s0 = (blk & 15) * 64;
        const float* Vb = V + ((size_t)bh * S_LEN + s0) * D_DIM;
        const int sr = tid >> 4, d4 = (tid & 15) * 4;
        #pragma unroll
        for (int ii = 0; ii < 4; ++ii) {
            const int s = sr + 16 * ii;
            float4 v = *(const float4*)(Vb + s * D_DIM + d4);
            t[(d4+0)*65 + s] = v.x; t[(d4+1)*65 + s] = v.y;
            t[(d4+2)*65 + s] = v.z; t[(d4+3)*65 + s] = v.w;
        }
        __syncthreads();
        const int d = tid >> 2, sq = tid & 3;
        ushort8v o0, o1;
        #pragma unroll
        for (int j = 0; j < 8; ++j) {
            o0[j] = f2bf(t[d*65 + sq*16 + j]);
            o1[j] = f2bf(t[d*65 + sq*16 + 8 + j]);
        }
        unsigned short* outp = Vt + ((size_t)bh * D_DIM + d) * S_LEN + s0 + sq * 16;
        *(ushort8v*)(outp)     = o0;
        *(ushort8v*)(outp + 8) = o1;
    }
}

// ---------- main ----------
__global__ __launch_bounds__(256, 3) void entmax_attn_mfma(
    const float* __restrict__ Q, const unsigned short* __restrict__ Kbf,
    const unsigned short* __restrict__ Vt, float* __restrict__ O)
{
    __shared__ __align__(16) unsigned short sQ[TQ * QPAD];      //  2304 B
    __shared__ __align__(16) unsigned short sP[TQ * PPAD];      // 33024 B
    __shared__ __align__(16) unsigned short sT[2][TK * D_DIM];  // 16384 B (dbuf K/V^T)
    __shared__ float sInv[TQ];

    const int tid  = threadIdx.x;
    const int lane = tid & 63;
    const int wave = tid >> 6;
    const int quad = lane >> 4;
    const int l15  = lane & 15;
    const int x7   = l15 & 7;

    // XCD swizzle: pin each bh's 64 blocks to one XCD (blockIdx%8 = XCD).
    const int xcd = blockIdx.x & 7;
    const int kk  = blockIdx.x >> 3;
    const int bh  = (xcd << 3) | (kk >> 6);
    const int qt  = kk & 63;

    const float* Qb = Q + ((size_t)bh * S_LEN + qt * TQ) * D_DIM;
    const unsigned short* Kb = Kbf + (size_t)bh * S_LEN * D_DIM;
    const unsigned short* Vb = Vt  + (size_t)bh * D_DIM * S_LEN;

    // staging geometry for 64x64 tiles (2 async16/thread), XOR chunk swizzle
    const int rl = lane >> 3;             // 0..7
    const int sc = (lane & 7) ^ rl;       // physical-chunk source (p = c ^ (r&7))

    // ---- stage Q tile (16x64 fp32 -> bf16, scale 1/16 folded in — exact) ----
    {
        const int r8 = tid >> 4, d04 = (tid & 15) * 4;
        float4 qv = *(const float4*)(Qb + r8 * D_DIM + d04);
        *(ushort4*)(&sQ[r8 * QPAD + d04]) =
            make_ushort4(f2bf(qv.x * 0.0625f), f2bf(qv.y * 0.0625f),
                         f2bf(qv.z * 0.0625f), f2bf(qv.w * 0.0625f));
    }
    // prefetch K tile 0
    #pragma unroll
    for (int inst = 0; inst < 2; ++inst) {
        const int r = wave * 16 + rl + inst * 8;
        async16(Kb + (size_t)r * D_DIM + sc * 8, &sT[0][wave * 1024 + inst * 512]);
    }
    __syncthreads();                       // sQ visible, K0 drained

    // hoisted A-fragments (constant across K-loop)
    short8 a0 = *(const short8*)(&sQ[l15 * QPAD + quad * 8]);
    short8 a1 = *(const short8*)(&sQ[l15 * QPAD + 32 + quad * 8]);

    // ================= GEMM1: scores = (Q/16).K^T, pipelined =================
    const int krow = wave * 16 + l15;      // this wave's score-col within tile
    for (int kt = 0; kt < NT; ++kt) {
        if (kt > 0) __syncthreads();       // drains prefetch kt (flew during kt-1)
        if (kt < NT - 1) {
            const unsigned short* Ksrc = Kb + (size_t)(kt + 1) * TK * D_DIM;
            unsigned short* dst = sT[(kt + 1) & 1];
            #pragma unroll
            for (int inst = 0; inst < 2; ++inst) {
                const int r = wave * 16 + rl + inst * 8;
                async16(Ksrc + (size_t)r * D_DIM + sc * 8, dst + wave * 1024 + inst * 512);
            }
        }
        const unsigned short* bt = sT[kt & 1];
        short8 b0 = *(const short8*)(bt + krow * D_DIM + ((quad)     ^ x7) * 8);
        short8 b1 = *(const short8*)(bt + krow * D_DIM + ((quad + 4) ^ x7) * 8);
        f32x4 acc = {0.f, 0.f, 0.f, 0.f};
        acc = __builtin_amdgcn_mfma_f32_16x16x32_bf16(a0, b0, acc, 0, 0, 0);
        acc = __builtin_amdgcn_mfma_f32_16x16x32_bf16(a1, b1, acc, 0, 0, 0);
        const int col = kt * TK + wave * 16 + l15;
        #pragma unroll
        for (int i = 0; i < 4; ++i)        // C: col=l15-derived, row=quad*4+i
            sP[(quad * 4 + i) * PPAD + col] = f2bf(acc[i]);
    }
    __syncthreads();                       // sP complete

    // prefetch V^T tile 0 (flies during entmax; drained at post-entmax barrier)
    #pragma unroll
    for (int inst = 0; inst < 2; ++inst) {
        const int r = wave * 16 + rl + inst * 8;         // r = d row
        async16(Vb + (size_t)r * S_LEN + sc * 8, &sT[0][wave * 1024 + inst * 512]);
    }

    // ========== entmax-1.5: row = wave*4+quad, barrier-free, b128 LDS ==========
    {
        const int myrow = wave * 4 + quad;
        unsigned short* prow = &sP[myrow * PPAD];
        float xv[64];
        #pragma unroll
        for (int i = 0; i < 8; ++i) {
            uint4 c4 = *(const uint4*)(prow + (i * 16 + l15) * 8);
            xv[i*8+0] = bf_lo(c4.x); xv[i*8+1] = bf_hi(c4.x);
            xv[i*8+2] = bf_lo(c4.y); xv[i*8+3] = bf_hi(c4.y);
            xv[i*8+4] = bf_lo(c4.z); xv[i*8+5] = bf_hi(c4.z);
            xv[i*8+6] = bf_lo(c4.w); xv[i*8+7] = bf_hi(c4.w);
        }
        float m0 = xv[0], m1 = xv[1], m2 = xv[2], m3 = xv[3];
        #pragma unroll
        for (int j = 4; j < 64; j += 4) {
            m0 = fmaxf(m0, xv[j]);   m1 = fmaxf(m1, xv[j+1]);
            m2 = fmaxf(m2, xv[j+2]); m3 = fmaxf(m3, xv[j+3]);
        }
        float m = fmaxf(fmaxf(m0, m1), fmaxf(m2, m3));
        #pragma unroll
        for (int off = 1; off < 16; off <<= 1) m = fmaxf(m, __shfl_xor(m, off));
        #pragma unroll
        for (int j = 0; j < 64; ++j) xv[j] -= m;        // max = 0, root in [-1,0)

        // Newton from below on convex decreasing g(tau)=sum (x-tau)+^2
        float tau = -1.0f;                               // g(-1) >= 1
        #pragma unroll 1
        for (int it = 0; it < 8; ++it) {
            float g0=0,g1=0,g2=0,g3=0, h0=0,h1=0,h2=0,h3=0;
            #pragma unroll
            for (int j = 0; j < 64; j += 4) {
                float t0 = fmaxf(xv[j]   - tau, 0.f);
                float t1 = fmaxf(xv[j+1] - tau, 0.f);
                float t2 = fmaxf(xv[j+2] - tau, 0.f);
                float t3 = fmaxf(xv[j+3] - tau, 0.f);
                g0 = fmaf(t0, t0, g0); h0 += t0;
                g1 = fmaf(t1, t1, g1); h1 += t1;
                g2 = fmaf(t2, t2, g2); h2 += t2;
                g3 = fmaf(t3, t3, g3); h3 += t3;
            }
            float g = (g0 + g1) + (g2 + g3);
            float h = (h0 + h1) + (h2 + h3);
            #pragma unroll
            for (int off = 1; off < 16; off <<= 1) {
                g += __shfl_xor(g, off);
                h += __shfl_xor(h, off);
            }
            tau += (g - 1.0f) / (2.0f * h);
        }

        // p = (x - tau)+^2 -> bf16, store b128, accumulate sum of rounded p
        float ps = 0.f;
        #pragma unroll
        for (int i = 0; i < 8; ++i) {
            uint4 o;
            unsigned pk[4];
            #pragma unroll
            for (int w = 0; w < 4; ++w) {
                float t0 = fmaxf(xv[i*8 + 2*w]     - tau, 0.f);
                float t1 = fmaxf(xv[i*8 + 2*w + 1] - tau, 0.f);
                unsigned b0 = f2bf(t0 * t0), b1 = f2bf(t1 * t1);
                ps += bf_lo(b0) + bf_lo(b1);
                pk[w] = b0 | (b1 << 16);
            }
            o.x = pk[0]; o.y = pk[1]; o.z = pk[2]; o.w = pk[3];
            *(uint4*)(prow + (i * 16 + l15) * 8) = o;
        }
        #pragma unroll
        for (int off = 1; off < 16; off <<= 1) ps += __shfl_xor(ps, off);
        if (l15 == 0) sInv[myrow] = 1.0f / ps;
    }
    __syncthreads();                       // p-values complete + V0 drained

    // ================= GEMM2: O = P . V, pipelined =================
    f32x4 oacc = {0.f, 0.f, 0.f, 0.f};
    const int n0 = wave * 16;
    for (int kt = 0; kt < NT; ++kt) {
        if (kt > 0) __syncthreads();
        if (kt < NT - 1) {
            const unsigned short* Vsrc = Vb + (kt + 1) * TK;
            unsigned short* dst = sT[(kt + 1) & 1];
            #pragma unroll
            for (int inst = 0; inst < 2; ++inst) {
                const int r = wave * 16 + rl + inst * 8;
                async16(Vsrc + (size_t)r * S_LEN + sc * 8, dst + wave * 1024 + inst * 512);
            }
        }
        const unsigned short* bt = sT[kt & 1];
        #pragma unroll
        for (int ks = 0; ks < 2; ++ks) {
            short8 a = *(const short8*)(&sP[l15 * PPAD + kt * TK + ks * 32 + quad * 8]);
            short8 b = *(const short8*)(bt + (n0 + l15) * D_DIM + ((ks * 4 + quad) ^ x7) * 8);
            oacc = __builtin_amdgcn_mfma_f32_16x16x32_bf16(a, b, oacc, 0, 0, 0);
        }
    }

    // ---- epilogue: renormalize + store ----
    float* Ob = O + ((size_t)bh * S_LEN + qt * TQ) * D_DIM;
    #pragma unroll
    for (int i = 0; i < 4; ++i) {
        const int row = quad * 4 + i;
        Ob[row * D_DIM + n0 + l15] = oacc[i] * sInv[row];
    }
}

extern "C" void kernel_launch(void* const* d_in, const int* in_sizes, int n_in,
                              void* d_out, int out_size, void* d_ws, size_t ws_size,
                              hipStream_t stream) {
    const float* q = (const float*)d_in[0];
    const float* k = (const float*)d_in[1];
    const float* v = (const float*)d_in[2];
    float* o = (float*)d_out;

    unsigned short* kbf = (unsigned short*)d_ws;                    // 8 MB
    unsigned short* vt  = kbf + (size_t)64 * S_LEN * D_DIM;         // 8 MB

    // fused prepass: 2048 K-convert blocks + 1024 V-transpose blocks
    prep_kv<<<3072, 256, 0, stream>>>(k, v, kbf, vt);
    // main: 64 bh x 64 q-tiles, XCD-swizzled
    entmax_attn_mfma<<<4096, 256, 0, stream>>>(q, kbf, vt, o);
}

// Round 7
// 200.314 us; speedup vs baseline: 20.0706x; 1.0333x over previous
//
#include <hip/hip_runtime.h>

// entmax-1.5 attention: B=8,H=8,S=1024,D=64, fp32 in/out.
// Prepass (fused): K -> bf16 ws; V -> bf16 transposed [bh][d][s] ws.
// Main: 16 q-rows/block; double-buffered 64x64 K/V tiles DMA'd via
// global_load_lds (prefetch overlapped with compute); GEMM1 Q.K^T -> bf16
// scores in LDS; per-row Newton for entmax tau (register-pinned scores,
// packed-f32 math, 16-lane reduces); GEMM2 P.V^T. XCD-swizzled grid.

#define S_LEN 1024
#define D_DIM 64
#define TQ    16
#define TK    64
#define NT    (S_LEN / TK)    // 16 tiles
#define QPAD  72              // sQ row stride (bf16 elems)
#define PPAD  1032            // sP row stride (bf16 elems)

typedef short  short8   __attribute__((ext_vector_type(8)));
typedef float  f32x4    __attribute__((ext_vector_type(4)));
typedef float  f32x2    __attribute__((ext_vector_type(2)));
typedef unsigned short ushort8v __attribute__((ext_vector_type(8)));

static __device__ __forceinline__ unsigned short f2bf(float f) {
    unsigned u = __builtin_bit_cast(unsigned, f);
    u += 0x7FFFu + ((u >> 16) & 1u);           // RNE
    return (unsigned short)(u >> 16);
}
static __device__ __forceinline__ float bf_lo(unsigned u) {
    return __builtin_bit_cast(float, u << 16);
}
static __device__ __forceinline__ float bf_hi(unsigned u) {
    return __builtin_bit_cast(float, u & 0xFFFF0000u);
}
static __device__ __forceinline__ void async16(const unsigned short* g, unsigned short* l) {
    __builtin_amdgcn_global_load_lds(
        (const __attribute__((address_space(1))) unsigned int*)g,
        (__attribute__((address_space(3))) unsigned int*)l, 16, 0, 0);
}

// ---------- fused prepass: K convert (blocks 0..2047), V transpose (2048..3071) ----------
__global__ __launch_bounds__(256) void prep_kv(
    const float* __restrict__ K, const float* __restrict__ V,
    unsigned short* __restrict__ Kbf, unsigned short* __restrict__ Vt)
{
    __shared__ float t[D_DIM * 65];
    const int tid = threadIdx.x;
    if (blockIdx.x < 2048) {
        const int idx = (blockIdx.x * 256 + tid) * 8;
        float4 a = *(const float4*)(K + idx);
        float4 b = *(const float4*)(K + idx + 4);
        ushort8v r;
        r[0]=f2bf(a.x); r[1]=f2bf(a.y); r[2]=f2bf(a.z); r[3]=f2bf(a.w);
        r[4]=f2bf(b.x); r[5]=f2bf(b.y); r[6]=f2bf(b.z); r[7]=f2bf(b.w);
        *(ushort8v*)(Kbf + idx) = r;
    } else {
        const int blk = blockIdx.x - 2048;
        const int bh = blk >> 4;
        const int s0 = (blk & 15) * 64;
        const float* Vb = V + ((size_t)bh * S_LEN + s0) * D_DIM;
        const int sr = tid >> 4, d4 = (tid & 15) * 4;
        #pragma unroll
        for (int ii = 0; ii < 4; ++ii) {
            const int s = sr + 16 * ii;
            float4 v = *(const float4*)(Vb + s * D_DIM + d4);
            t[(d4+0)*65 + s] = v.x; t[(d4+1)*65 + s] = v.y;
            t[(d4+2)*65 + s] = v.z; t[(d4+3)*65 + s] = v.w;
        }
        __syncthreads();
        const int d = tid >> 2, sq = tid & 3;
        ushort8v o0, o1;
        #pragma unroll
        for (int j = 0; j < 8; ++j) {
            o0[j] = f2bf(t[d*65 + sq*16 + j]);
            o1[j] = f2bf(t[d*65 + sq*16 + 8 + j]);
        }
        unsigned short* outp = Vt + ((size_t)bh * D_DIM + d) * S_LEN + s0 + sq * 16;
        *(ushort8v*)(outp)     = o0;
        *(ushort8v*)(outp + 8) = o1;
    }
}

// ---------- main ----------
__global__ __launch_bounds__(256, 3) void entmax_attn_mfma(
    const float* __restrict__ Q, const unsigned short* __restrict__ Kbf,
    const unsigned short* __restrict__ Vt, float* __restrict__ O)
{
#pragma clang fp contract(fast)
    __shared__ __align__(16) unsigned short sQ[TQ * QPAD];      //  2304 B
    __shared__ __align__(16) unsigned short sP[TQ * PPAD];      // 33024 B
    __shared__ __align__(16) unsigned short sT[2][TK * D_DIM];  // 16384 B (dbuf K/V^T)
    __shared__ float sInv[TQ];

    const int tid  = threadIdx.x;
    const int lane = tid & 63;
    const int wave = tid >> 6;
    const int quad = lane >> 4;
    const int l15  = lane & 15;
    const int x7   = l15 & 7;

    // XCD swizzle: pin each bh's 64 blocks to one XCD (blockIdx%8 = XCD).
    const int xcd = blockIdx.x & 7;
    const int kk  = blockIdx.x >> 3;
    const int bh  = (xcd << 3) | (kk >> 6);
    const int qt  = kk & 63;

    const float* Qb = Q + ((size_t)bh * S_LEN + qt * TQ) * D_DIM;
    const unsigned short* Kb = Kbf + (size_t)bh * S_LEN * D_DIM;
    const unsigned short* Vb = Vt  + (size_t)bh * D_DIM * S_LEN;

    // staging geometry for 64x64 tiles (2 async16/thread), XOR chunk swizzle
    const int rl = lane >> 3;             // 0..7
    const int sc = (lane & 7) ^ rl;       // physical-chunk source (p = c ^ (r&7))

    // ---- stage Q tile (16x64 fp32 -> bf16, scale 1/16 folded in — exact) ----
    {
        const int r8 = tid >> 4, d04 = (tid & 15) * 4;
        float4 qv = *(const float4*)(Qb + r8 * D_DIM + d04);
        *(ushort4*)(&sQ[r8 * QPAD + d04]) =
            make_ushort4(f2bf(qv.x * 0.0625f), f2bf(qv.y * 0.0625f),
                         f2bf(qv.z * 0.0625f), f2bf(qv.w * 0.0625f));
    }
    // prefetch K tile 0
    #pragma unroll
    for (int inst = 0; inst < 2; ++inst) {
        const int r = wave * 16 + rl + inst * 8;
        async16(Kb + (size_t)r * D_DIM + sc * 8, &sT[0][wave * 1024 + inst * 512]);
    }
    __syncthreads();                       // sQ visible, K0 drained

    // hoisted A-fragments (constant across K-loop)
    short8 a0 = *(const short8*)(&sQ[l15 * QPAD + quad * 8]);
    short8 a1 = *(const short8*)(&sQ[l15 * QPAD + 32 + quad * 8]);

    // ================= GEMM1: scores = (Q/16).K^T, pipelined =================
    const int krow = wave * 16 + l15;      // this wave's score-col within tile
    for (int kt = 0; kt < NT; ++kt) {
        if (kt > 0) __syncthreads();       // drains prefetch kt (flew during kt-1)
        if (kt < NT - 1) {
            const unsigned short* Ksrc = Kb + (size_t)(kt + 1) * TK * D_DIM;
            unsigned short* dst = sT[(kt + 1) & 1];
            #pragma unroll
            for (int inst = 0; inst < 2; ++inst) {
                const int r = wave * 16 + rl + inst * 8;
                async16(Ksrc + (size_t)r * D_DIM + sc * 8, dst + wave * 1024 + inst * 512);
            }
        }
        const unsigned short* bt = sT[kt & 1];
        short8 b0 = *(const short8*)(bt + krow * D_DIM + ((quad)     ^ x7) * 8);
        short8 b1 = *(const short8*)(bt + krow * D_DIM + ((quad + 4) ^ x7) * 8);
        f32x4 acc = {0.f, 0.f, 0.f, 0.f};
        acc = __builtin_amdgcn_mfma_f32_16x16x32_bf16(a0, b0, acc, 0, 0, 0);
        acc = __builtin_amdgcn_mfma_f32_16x16x32_bf16(a1, b1, acc, 0, 0, 0);
        const int col = kt * TK + wave * 16 + l15;
        #pragma unroll
        for (int i = 0; i < 4; ++i)        // C: col=l15-derived, row=quad*4+i
            sP[(quad * 4 + i) * PPAD + col] = f2bf(acc[i]);
    }
    __syncthreads();                       // sP complete

    // prefetch V^T tile 0 (flies during entmax; drained at post-entmax barrier)
    #pragma unroll
    for (int inst = 0; inst < 2; ++inst) {
        const int r = wave * 16 + rl + inst * 8;         // r = d row
        async16(Vb + (size_t)r * S_LEN + sc * 8, &sT[0][wave * 1024 + inst * 512]);
    }

    // ========== entmax-1.5: row = wave*4+quad, packed-f32, reg-pinned ==========
    {
        const int myrow = wave * 4 + quad;
        unsigned short* prow = &sP[myrow * PPAD];
        f32x2 xp[32];
        #pragma unroll
        for (int i = 0; i < 8; ++i) {
            uint4 c4 = *(const uint4*)(prow + (i * 16 + l15) * 8);
            xp[i*4+0] = (f32x2){bf_lo(c4.x), bf_hi(c4.x)};
            xp[i*4+1] = (f32x2){bf_lo(c4.y), bf_hi(c4.y)};
            xp[i*4+2] = (f32x2){bf_lo(c4.z), bf_hi(c4.z)};
            xp[i*4+3] = (f32x2){bf_lo(c4.w), bf_hi(c4.w)};
        }
        // pin the score array to VGPRs (defeat rematerialization; LDS caps
        // occupancy at 3 blocks/CU so ~140 VGPRs is free)
        #pragma unroll
        for (int j = 0; j < 32; ++j) {
            double d = __builtin_bit_cast(double, xp[j]);
            asm volatile("" : "+v"(d));
            xp[j] = __builtin_bit_cast(f32x2, d);
        }

        f32x2 mm = xp[0];
        #pragma unroll
        for (int j = 1; j < 32; ++j) mm = __builtin_elementwise_max(mm, xp[j]);
        float m = fmaxf(mm[0], mm[1]);
        #pragma unroll
        for (int off = 1; off < 16; off <<= 1) m = fmaxf(m, __shfl_xor(m, off));

        // Newton from below on convex decreasing g(tau)=sum (x-tau)+^2;
        // raw coordinates: root in [m-1, m), g(m-1) >= 1, monotone from below.
        const f32x2 z2 = {0.f, 0.f};
        float tau = m - 1.0f;
        #pragma unroll 1
        for (int it = 0; it < 8; ++it) {
            f32x2 g2 = z2, h2 = z2;
            const f32x2 t2 = {tau, tau};
            #pragma unroll
            for (int j = 0; j < 32; ++j) {
                f32x2 t = __builtin_elementwise_max(xp[j] - t2, z2);
                g2 = t * t + g2;               // contracts to v_pk_fma_f32
                h2 = h2 + t;
            }
            float g = g2[0] + g2[1], h = h2[0] + h2[1];
            #pragma unroll
            for (int off = 1; off < 16; off <<= 1) {
                g += __shfl_xor(g, off);
                h += __shfl_xor(h, off);
            }
            tau += (g - 1.0f) * __builtin_amdgcn_rcpf(h + h);
        }

        // p = (x - tau)+^2 -> bf16, b128 stores, accumulate sum of rounded p
        float ps = 0.f;
        const f32x2 tv = {tau, tau};
        #pragma unroll
        for (int i = 0; i < 8; ++i) {
            unsigned pk[4];
            #pragma unroll
            for (int w = 0; w < 4; ++w) {
                f32x2 t = __builtin_elementwise_max(xp[i*4+w] - tv, z2);
                f32x2 p = t * t;
                unsigned b0 = f2bf(p[0]), b1 = f2bf(p[1]);
                ps += bf_lo(b0) + bf_lo(b1);
                pk[w] = b0 | (b1 << 16);
            }
            uint4 o; o.x = pk[0]; o.y = pk[1]; o.z = pk[2]; o.w = pk[3];
            *(uint4*)(prow + (i * 16 + l15) * 8) = o;
        }
        #pragma unroll
        for (int off = 1; off < 16; off <<= 1) ps += __shfl_xor(ps, off);
        if (l15 == 0) sInv[myrow] = 1.0f / ps;
    }
    __syncthreads();                       // p-values complete + V0 drained

    // ================= GEMM2: O = P . V, pipelined =================
    f32x4 oacc = {0.f, 0.f, 0.f, 0.f};
    const int n0 = wave * 16;
    for (int kt = 0; kt < NT; ++kt) {
        if (kt > 0) __syncthreads();
        if (kt < NT - 1) {
            const unsigned short* Vsrc = Vb + (kt + 1) * TK;
            unsigned short* dst = sT[(kt + 1) & 1];
            #pragma unroll
            for (int inst = 0; inst < 2; ++inst) {
                const int r = wave * 16 + rl + inst * 8;
                async16(Vsrc + (size_t)r * S_LEN + sc * 8, dst + wave * 1024 + inst * 512);
            }
        }
        const unsigned short* bt = sT[kt & 1];
        #pragma unroll
        for (int ks = 0; ks < 2; ++ks) {
            short8 a = *(const short8*)(&sP[l15 * PPAD + kt * TK + ks * 32 + quad * 8]);
            short8 b = *(const short8*)(bt + (n0 + l15) * D_DIM + ((ks * 4 + quad) ^ x7) * 8);
            oacc = __builtin_amdgcn_mfma_f32_16x16x32_bf16(a, b, oacc, 0, 0, 0);
        }
    }

    // ---- epilogue: renormalize + store ----
    float* Ob = O + ((size_t)bh * S_LEN + qt * TQ) * D_DIM;
    #pragma unroll
    for (int i = 0; i < 4; ++i) {
        const int row = quad * 4 + i;
        Ob[row * D_DIM + n0 + l15] = oacc[i] * sInv[row];
    }
}

extern "C" void kernel_launch(void* const* d_in, const int* in_sizes, int n_in,
                              void* d_out, int out_size, void* d_ws, size_t ws_size,
                              hipStream_t stream) {
    const float* q = (const float*)d_in[0];
    const float* k = (const float*)d_in[1];
    const float* v = (const float*)d_in[2];
    float* o = (float*)d_out;

    unsigned short* kbf = (unsigned short*)d_ws;                    // 8 MB
    unsigned short* vt  = kbf + (size_t)64 * S_LEN * D_DIM;         // 8 MB

    // fused prepass: 2048 K-convert blocks + 1024 V-transpose blocks
    prep_kv<<<3072, 256, 0, stream>>>(k, v, kbf, vt);
    // main: 64 bh x 64 q-tiles, XCD-swizzled
    entmax_attn_mfma<<<4096, 256, 0, stream>>>(q, kbf, vt, o);
}